// Round 1
// baseline (99.760 us; speedup 1.0000x reference)
//
#include <hip/hip_runtime.h>
#include <hip/hip_fp16.h>

typedef __attribute__((ext_vector_type(8))) _Float16 f16x8;
typedef __attribute__((ext_vector_type(4))) _Float16 f16x4;
typedef __attribute__((ext_vector_type(8))) unsigned short u16x8;
typedef __attribute__((ext_vector_type(4))) float f32x4;

constexpr int NT = 256;
constexpr int TILE_SHORTS = 4096;   // 64 rows x 64 fp16 = 8KB tile image

// phys 16B-chunk swizzle: row r, logical chunk c (0..7) -> short offset
__device__ __forceinline__ int swzoff(int row, int c) {
    return row * 64 + ((c ^ (row & 7)) << 3);
}
__device__ __forceinline__ unsigned short f2h_u(float x) {
    return __half_as_ushort(__float2half(x));
}

// ============ pre-pass: f32 -> fp16 swizzled tile images in ws ============
// XCD-pinned mapping: bid%8 == bh>>1, so the image is produced in the L2
// of the XCD whose main-kernel blocks will consume it.
__global__ __launch_bounds__(256, 4) void prepass(
    const float* __restrict__ Kg, const float* __restrict__ Vg,
    unsigned short* __restrict__ Kw, unsigned short* __restrict__ Vw)
{
    __shared__ __align__(16) float Vl[64 * 68];
    const int bid  = (int)blockIdx.x;          // 0..511
    const int xcd  = bid & 7;
    const int y    = bid >> 3;                 // 0..63
    const int bh   = xcd * 2 + (y >= 32);      // 2 bh per XCD
    const int tile = y & 31;                   // 0..31
    const int b = bh >> 3, h = bh & 7;
    const int tid = threadIdx.x;
    const size_t gbase = (((size_t)b * 2048 + tile * 64) * 8 + h) * 64;

    // stage V tile f32 into LDS (coalesced)
    #pragma unroll
    for (int j = 0; j < 4; ++j) {
        int id = j * 256 + tid, row = id >> 4, c4 = id & 15;
        *(float4*)&Vl[row * 68 + c4 * 4] =
            *(const float4*)&Vg[gbase + (size_t)row * 512 + c4 * 4];
    }

    // K image: row-major fp16, 16B chunks XOR-swizzled
    unsigned short* Ko = Kw + (size_t)(bh * 32 + tile) * TILE_SHORTS;
    #pragma unroll
    for (int j = 0; j < 2; ++j) {
        int id = j * 256 + tid, row = id >> 3, c = id & 7;
        const float* src = &Kg[gbase + (size_t)row * 512 + c * 8];
        float4 x = *(const float4*)src, y2 = *(const float4*)(src + 4);
        u16x8 o;
        o[0] = f2h_u(x.x); o[1] = f2h_u(x.y); o[2] = f2h_u(x.z); o[3] = f2h_u(x.w);
        o[4] = f2h_u(y2.x); o[5] = f2h_u(y2.y); o[6] = f2h_u(y2.z); o[7] = f2h_u(y2.w);
        *(u16x8*)&Ko[swzoff(row, c)] = o;
    }
    __syncthreads();

    // V^T image, k-permuted so one b128 = the 4 B-frags of 16x16x16 PV:
    // store at k' = quad*16 + c*4 + i the element k = c*16 + quad*4 + i
    unsigned short* Vo = Vw + (size_t)(bh * 32 + tile) * TILE_SHORTS;
    #pragma unroll
    for (int j = 0; j < 2; ++j) {
        int id = j * 256 + tid, vrow = id >> 3, g = id & 7;
        u16x8 o;
        #pragma unroll
        for (int jj = 0; jj < 8; ++jj) {
            int kk = ((g & 1) * 2 + (jj >> 2)) * 16 + (g >> 1) * 4 + (jj & 3);
            o[jj] = f2h_u(Vl[kk * 68 + vrow]);
        }
        *(u16x8*)&Vo[swzoff(vrow, g)] = o;
    }
}

// ============ main kernel: XCD-pinned bh + 2-deep A/B register prefetch ====
__global__ __launch_bounds__(NT, 3) void attn_pow2_f16(
    const float* __restrict__ Qg,
    const unsigned short* __restrict__ Kw, const unsigned short* __restrict__ Vw,
    float* __restrict__ Og)
{
    __shared__ __align__(16) unsigned short lds[4 * TILE_SHORTS];  // 32 KiB
    unsigned short* const Kb = lds;                    // bufA/bufB K
    unsigned short* const Vb = lds + 2 * TILE_SHORTS;  // bufA/bufB V
    const int tid  = threadIdx.x;
    const int lane = tid & 63;
    const int wave = tid >> 6;
    const int a    = lane & 15;
    const int quad = lane >> 4;
    const int m0   = wave * 16;

    // XCD-pinned + heavy/light paired mapping:
    //   bid%8 = xcd -> bh pair {2x, 2x+1}; first dispatch round (y<32) covers
    //   bh=2x with qt=31-yy (heavy first), second round bh=2x+1 with qt=yy.
    //   CU c of each XCD gets qt=31-c and qt=c -> 33 tile-iters each.
    const int bid = (int)blockIdx.x;
    const int xcd = bid & 7;
    const int y   = bid >> 3;
    const int yy  = y & 31;
    const int bh  = xcd * 2 + (y >= 32);
    const int qt  = (y < 32) ? (31 - yy) : yy;
    const int b = bh >> 3, h = bh & 7;
    const int q0 = qt * 64;

    // ---- Q B-frags from global f32: B[n=q=a][k=d=ks*32+quad*8+j] ----
    f16x8 bQ[2];
    {
        const size_t qrowbase = (((size_t)b * 2048 + q0 + m0 + a) * 8 + h) * 64;
        #pragma unroll
        for (int ks = 0; ks < 2; ++ks) {
            const float* src = &Qg[qrowbase + ks * 32 + quad * 8];
            float4 x = *(const float4*)src, y2 = *(const float4*)(src + 4);
            u16x8 o;
            o[0] = f2h_u(x.x); o[1] = f2h_u(x.y); o[2] = f2h_u(x.z); o[3] = f2h_u(x.w);
            o[4] = f2h_u(y2.x); o[5] = f2h_u(y2.y); o[6] = f2h_u(y2.z); o[7] = f2h_u(y2.w);
            bQ[ks] = __builtin_bit_cast(f16x8, o);
        }
    }

    const unsigned short* Ktiles = Kw + (size_t)bh * 32 * TILE_SHORTS;
    const unsigned short* Vtiles = Vw + (size_t)bh * 32 * TILE_SHORTS;

    // 2-deep register-staged prefetch, named stages (no runtime indexing)
    u16x8 rKA[2], rVA[2], rKB[2], rVB[2];
    auto gloadA = [&](int kt) {
        const u16x8* kg = (const u16x8*)(Ktiles + (size_t)kt * TILE_SHORTS);
        const u16x8* vg = (const u16x8*)(Vtiles + (size_t)kt * TILE_SHORTS);
        rKA[0] = kg[tid * 2]; rKA[1] = kg[tid * 2 + 1];
        rVA[0] = vg[tid * 2]; rVA[1] = vg[tid * 2 + 1];
    };
    auto gloadB = [&](int kt) {
        const u16x8* kg = (const u16x8*)(Ktiles + (size_t)kt * TILE_SHORTS);
        const u16x8* vg = (const u16x8*)(Vtiles + (size_t)kt * TILE_SHORTS);
        rKB[0] = kg[tid * 2]; rKB[1] = kg[tid * 2 + 1];
        rVB[0] = vg[tid * 2]; rVB[1] = vg[tid * 2 + 1];
    };

    f32x4 oacc[4];
    #pragma unroll
    for (int n = 0; n < 4; ++n) oacc[n] = (f32x4){0.f, 0.f, 0.f, 0.f};
    float den_l = 0.f;

    union U8 { u16x8 u; f16x4 q[2]; f16x8 f; };

    auto compute = [&](const unsigned short* Kc, const unsigned short* Vc,
                       bool diag) {
        // ---- S^T = K·Q^T per 16-row k-strip: C-layout == A-layout of S ----
        f32x4 sacc[4];
        #pragma unroll
        for (int s = 0; s < 4; ++s) sacc[s] = (f32x4){0.f, 0.f, 0.f, 0.f};
        #pragma unroll
        for (int s = 0; s < 4; ++s) {
            #pragma unroll
            for (int ks = 0; ks < 2; ++ks) {
                U8 ak; ak.u = *(const u16x8*)&Kc[swzoff(s * 16 + a, ks * 4 + quad)];
                sacc[s] = __builtin_amdgcn_mfma_f32_16x16x32_f16(ak.f, bQ[ks], sacc[s], 0, 0, 0);
            }
        }

        // ---- square, mask (diag), den, convert in-register ----
        f16x4 aS[4];
        #pragma unroll
        for (int s = 0; s < 4; ++s) {
            float p[4];
            #pragma unroll
            for (int r = 0; r < 4; ++r) {
                float d0 = sacc[s][r];
                float v = d0 * d0;
                if (diag && (s * 16 + quad * 4 + r) > (m0 + a)) v = 0.f;
                p[r] = v;
            }
            den_l += (p[0] + p[1]) + (p[2] + p[3]);
            aS[s] = (f16x4){(_Float16)p[0], (_Float16)p[1], (_Float16)p[2], (_Float16)p[3]};
        }

        // ---- PV: O += S·V via 16x16x16, S^T C-regs feed A directly ----
        #pragma unroll
        for (int n = 0; n < 4; ++n) {
            U8 va, vb;
            va.u = *(const u16x8*)&Vc[swzoff(n * 16 + a, quad * 2)];
            vb.u = *(const u16x8*)&Vc[swzoff(n * 16 + a, quad * 2 + 1)];
            oacc[n] = __builtin_amdgcn_mfma_f32_16x16x16f16(aS[0], va.q[0], oacc[n], 0, 0, 0);
            oacc[n] = __builtin_amdgcn_mfma_f32_16x16x16f16(aS[1], va.q[1], oacc[n], 0, 0, 0);
            oacc[n] = __builtin_amdgcn_mfma_f32_16x16x16f16(aS[2], vb.q[0], oacc[n], 0, 0, 0);
            oacc[n] = __builtin_amdgcn_mfma_f32_16x16x16f16(aS[3], vb.q[1], oacc[n], 0, 0, 0);
        }
    };

    // prologue: fill both stages (loads for tile kt have 2 phases to land)
    gloadA(0);
    if (qt >= 1) gloadB(1);

    int kt = 0;
    for (;;) {
        // ---- A phase: tile kt (even) ----
        {
            u16x8* kd = (u16x8*)Kb;
            u16x8* vd = (u16x8*)Vb;
            kd[tid * 2] = rKA[0]; kd[tid * 2 + 1] = rKA[1];
            vd[tid * 2] = rVA[0]; vd[tid * 2 + 1] = rVA[1];
        }
        __syncthreads();                 // bufA complete; WAR is 1 barrier back
        if (kt + 2 <= qt) gloadA(kt + 2);   // in flight across 2 compute phases
        compute(Kb, Vb, kt == qt);
        if (++kt > qt) break;

        // ---- B phase: tile kt (odd) ----
        {
            u16x8* kd = (u16x8*)(Kb + TILE_SHORTS);
            u16x8* vd = (u16x8*)(Vb + TILE_SHORTS);
            kd[tid * 2] = rKB[0]; kd[tid * 2 + 1] = rKB[1];
            vd[tid * 2] = rVB[0]; vd[tid * 2 + 1] = rVB[1];
        }
        __syncthreads();
        if (kt + 2 <= qt) gloadB(kt + 2);
        compute(Kb + TILE_SHORTS, Vb + TILE_SHORTS, kt == qt);
        if (++kt > qt) break;
    }

    // ---- den: reduce across quads (same q=a), then gather per output row ----
    den_l += __shfl_xor(den_l, 16);
    den_l += __shfl_xor(den_l, 32);

    float invz[4];
    #pragma unroll
    for (int r = 0; r < 4; ++r) {
        float dq = __shfl(den_l, quad * 4 + r);   // lane holding a == quad*4+r
        invz[r] = 1.0f / (dq + 1e-5f);
    }

    #pragma unroll
    for (int n = 0; n < 4; ++n) {
        #pragma unroll
        for (int r = 0; r < 4; ++r) {
            int t = q0 + m0 + quad * 4 + r;
            int v = n * 16 + a;
            Og[(((size_t)b * 2048 + t) * 8 + h) * 64 + v] = oacc[n][r] * invz[r];
        }
    }
}

extern "C" void kernel_launch(void* const* d_in, const int* in_sizes, int n_in,
                              void* d_out, int out_size, void* d_ws, size_t ws_size,
                              hipStream_t stream) {
    const float* Q = (const float*)d_in[0];
    const float* K = (const float*)d_in[1];
    const float* V = (const float*)d_in[2];
    float* O = (float*)d_out;
    unsigned short* Kw = (unsigned short*)d_ws;                 // 4 MB
    unsigned short* Vw = Kw + (size_t)16 * 32 * TILE_SHORTS;    // 4 MB

    prepass<<<dim3(512), 256, 0, stream>>>(K, V, Kw, Vw);
    attn_pow2_f16<<<dim3(512), NT, 0, stream>>>(Q, Kw, Vw, O);
}